// Round 1
// baseline (1037.856 us; speedup 1.0000x reference)
//
#include <hip/hip_runtime.h>
#include <hip/hip_bf16.h>
#include <math.h>

// Problem constants
#define TT   128
#define BB   256
#define DIN  256
#define DH   1024
#define DOUT 256

// R3-proven shape: 8 row-groups (32 rows) x 32 col-blocks (32 cols), 128 thr,
// 512 blocks, 64KB LDS -> co-resident. R9 flagless sync (epoch bit stolen from
// each bf16 LSB; every 8B word self-validates; AGLD/AGST agent-scope only; no
// fences, no flags, no barriers in the loop). R11: H in MFMA B-fragment order
// so the exchange is fully coalesced.
//
// R12 change: FULL-DEPTH OVERLAP. The step was latency-bound (5.5us/step vs
// ~1us floor; MfmaUtil 4.8%):
//  (a) all 4 h-chunk prefetches issued at step top (64 loads in flight),
//  (b) validate/consume chunks IN ANY ORDER via a done-mask round-robin; a
//      failed chunk is re-issued immediately so retries overlap instead of
//      chaining (f32 accumulation order is irrelevant at this tolerance),
//  (c) xs is software-pipelined one step ahead in registers (the 32KB/block
//      HBM-cold x-tile RTT no longer sits in the serial chain),
//  (d) 4 accumulator chains (chunk-parity split) halve dependent-MFMA depth.
#define NGM 8
#define MR  32
#define NGN 32
#define NC  32

typedef float  floatx4 __attribute__((ext_vector_type(4)));
typedef short  shortx8 __attribute__((ext_vector_type(8)));
typedef unsigned long long u64;

#define CMASK 0x0001000100010001ULL
#define GSTRIDE 32768           // shorts per group slab (2*32*4*16*8)

__device__ __forceinline__ short f2bf(float f) {
    union { float f; unsigned u; } v; v.f = f;
    unsigned r = v.u + 0x7fffu + ((v.u >> 16) & 1u);   // RNE, inputs never NaN
    return (short)(r >> 16);
}

// RNE to the bf16 grid restricted to LSB==bit (step 2 ulp): err <= 1 ulp bf16
__device__ __forceinline__ unsigned short bf15e(float v, unsigned bit) {
    union { float f; unsigned u; } x; x.f = v;
    unsigned ua = x.u - (bit << 16);
    unsigned k  = (ua + 0xFFFFu + ((ua >> 17) & 1u)) >> 17;
    return (unsigned short)((k << 1) | bit);
}

__device__ __forceinline__ shortx8 mk8(u64 lo, u64 hi) {
    union { struct { u64 a, b; } s; shortx8 v; } u;
    u.s.a = lo; u.s.b = hi;
    return u.v;
}

__device__ __forceinline__ float fast_tanh(float z) {
    float e = __expf(2.0f * fabsf(z));
    float r = 1.0f - 2.0f / (e + 1.0f);
    return copysignf(r, z);
}

#define AGLD(p)    __hip_atomic_load((p),  __ATOMIC_RELAXED, __HIP_MEMORY_SCOPE_AGENT)
#define AGST(p, v) __hip_atomic_store((p), (v), __ATOMIC_RELAXED, __HIP_MEMORY_SCOPE_AGENT)

// hfr = group slab base + rt*16384 + q*128 + lr*8 ; frag ks at +ks*512.
// One chunk = 8 ks fragments = 16 u64 AGLDs, COALESCED across lanes.
#define LD16(buf, base) do { \
    _Pragma("unroll") \
    for (int _j = 0; _j < 8; ++_j) { \
        const u64* _p = (const u64*)(hfr + ((base) + _j) * 512); \
        buf[2 * _j]     = AGLD(_p); \
        buf[2 * _j + 1] = AGLD(_p + 1); \
    } } while (0)
#define OK16(buf, okvar) do { \
    int _o = 1; \
    _Pragma("unroll") \
    for (int _j = 0; _j < 16; ++_j) _o &= ((buf[_j] & CMASK) == pat); \
    okvar = __all(_o); } while (0)
#define CONS16(buf, base, accX, accY) do { \
    _Pragma("unroll") \
    for (int _j = 0; _j < 8; ++_j) { \
        shortx8 bfr = mk8(buf[2 * _j], buf[2 * _j + 1]); \
        shortx8 a0 = *(const shortx8*)&WhL[(base) + _j][0][q][lr][0]; \
        shortx8 a1 = *(const shortx8*)&WhL[(base) + _j][1][q][lr][0]; \
        accX = __builtin_amdgcn_mfma_f32_16x16x32_bf16(a0, bfr, accX, 0, 0, 0); \
        accY = __builtin_amdgcn_mfma_f32_16x16x32_bf16(a1, bfr, accY, 0, 0, 0); \
    } } while (0)

__global__ __launch_bounds__(128, 1) void rnn_steps_kernel(
    const float* __restrict__ xs, const float* __restrict__ W1x,
    const float* __restrict__ W1h, const float* __restrict__ b1,
    short* __restrict__ Hbuf)
{
    const int gm  = blockIdx.x;   // 0..7 row group
    const int gn  = blockIdx.y;   // 0..31 col block
    const int tid = threadIdx.x;
    const int w   = tid >> 6;     // wave -> 16-row tile
    const int l   = tid & 63;
    const int lr  = l & 15;
    const int q   = l >> 4;       // MFMA k-quad

    const int r0 = gm * MR;
    const int c0 = gn * NC;

    // W1h slice as MFMA A-fragments in LDS (R3-proven layout)
    __shared__ short WhL[DH / 32][2][4][16][8];   // 64 KB
    for (int idx = tid; idx < (DH / 32) * 2 * 4 * 16; idx += 128) {
        const int c  = idx & 15;
        const int qq = (idx >> 4) & 3;
        const int ct = (idx >> 6) & 1;
        const int ks = idx >> 7;
        shortx8 f;
        #pragma unroll
        for (int j = 0; j < 8; ++j)
            f[j] = f2bf(W1h[(size_t)(ks * 32 + qq * 8 + j) * DH + c0 + ct * 16 + c]);
        *(shortx8*)&WhL[ks][ct][qq][c][0] = f;
    }
    // W1x A-fragments register-resident (32 VGPRs)
    shortx8 wx[2][8];
    #pragma unroll
    for (int ct = 0; ct < 2; ++ct)
        #pragma unroll
        for (int ks = 0; ks < 8; ++ks) {
            shortx8 f;
            #pragma unroll
            for (int j = 0; j < 8; ++j)
                f[j] = f2bf(W1x[(size_t)(ks * 32 + q * 8 + j) * DH + c0 + ct * 16 + lr]);
            wx[ct][ks] = f;
        }
    __syncthreads();   // WhL ready; no barriers after this point

    floatx4 bias[2];
    #pragma unroll
    for (int ct = 0; ct < 2; ++ct)
        #pragma unroll
        for (int r = 0; r < 4; ++r) bias[ct][r] = b1[c0 + ct * 16 + q * 4 + r];

    const int myrow = r0 + w * 16 + lr;        // xs rows (unchanged)
    const size_t HS = (size_t)BB * DH;         // shorts per version

    // fragment-layout bases (consumer reads its own row-tile w)
    short* const Hg   = Hbuf + gm * GSTRIDE;
    const int rdoff   = w * 16384 + q * 128 + lr * 8;
    // producer store offsets (ks=gn): [w][gn][ct*2+(q>>1)][lr][(q&1)*4]
    const int wroff   = w * 16384 + gn * 512 + (q >> 1) * 128 + lr * 8 + (q & 1) * 4;

    // ---- xs register pipeline: xf holds x_t, loaded during step t-1 ----
    floatx4 xf[16];
    {
        const float* xrow = xs + (size_t)myrow * DIN + q * 8;   // t = 1
        #pragma unroll
        for (int ks = 0; ks < 8; ++ks) {
            xf[2 * ks]     = *(const floatx4*)(xrow + ks * 32);
            xf[2 * ks + 1] = *(const floatx4*)(xrow + ks * 32 + 4);
        }
    }

    for (int t = 1; t <= TT; ++t) {
        const short* const hfr = Hg + (size_t)((t - 1) & 1) * HS + rdoff;
        // expected epoch code for h_{t-1}: 1+((t-2)%15) in [1,15]; t=1 unused.
        const int pc = (t >= 2) ? (1 + ((t - 2) % 15)) : 0;
        const u64 pat = ((u64)(pc & 1)) | ((u64)((pc >> 1) & 1) << 16) |
                        ((u64)((pc >> 2) & 1) << 32) | ((u64)((pc >> 3) & 1) << 48);

        // ---- deep prefetch: ALL 4 h-chunks in flight before anything else ----
        u64 bA[16], bB[16], bC[16], bD[16];
        if (t > 1) { LD16(bA, 0); LD16(bB, 8); LD16(bC, 16); LD16(bD, 24); }

        floatx4 accA0 = {0.f, 0.f, 0.f, 0.f}, accA1 = {0.f, 0.f, 0.f, 0.f};
        floatx4 accB0 = {0.f, 0.f, 0.f, 0.f}, accB1 = {0.f, 0.f, 0.f, 0.f};

        // ---- x_t @ W1x from the register pipeline (no memory on this path) ----
        #pragma unroll
        for (int ks = 0; ks < 8; ++ks) {
            floatx4 x0 = xf[2 * ks], x1 = xf[2 * ks + 1];
            shortx8 b;
            b[0] = f2bf(x0[0]); b[1] = f2bf(x0[1]); b[2] = f2bf(x0[2]); b[3] = f2bf(x0[3]);
            b[4] = f2bf(x1[0]); b[5] = f2bf(x1[1]); b[6] = f2bf(x1[2]); b[7] = f2bf(x1[3]);
            accA0 = __builtin_amdgcn_mfma_f32_16x16x32_bf16(wx[0][ks], b, accA0, 0, 0, 0);
            accA1 = __builtin_amdgcn_mfma_f32_16x16x32_bf16(wx[1][ks], b, accA1, 0, 0, 0);
        }

        // ---- fire xs loads for step t+1 (consumed next iteration) ----
        if (t < TT) {
            const float* xrow = xs + ((size_t)t * BB + myrow) * DIN + q * 8;
            #pragma unroll
            for (int ks = 0; ks < 8; ++ks) {
                xf[2 * ks]     = *(const floatx4*)(xrow + ks * 32);
                xf[2 * ks + 1] = *(const floatx4*)(xrow + ks * 32 + 4);
            }
        }

        // ---- h_{t-1} @ W1h: consume chunks in ARRIVAL order; failed chunks
        //      are re-issued immediately so all retry RTTs overlap ----
        if (t > 1) {
            int done = 0;
            while (done != 0xF) {
                if (!(done & 1)) {
                    int ok; OK16(bA, ok);
                    if (ok) { CONS16(bA, 0, accA0, accA1); done |= 1; } else LD16(bA, 0);
                }
                if (!(done & 2)) {
                    int ok; OK16(bB, ok);
                    if (ok) { CONS16(bB, 8, accB0, accB1); done |= 2; } else LD16(bB, 8);
                }
                if (!(done & 4)) {
                    int ok; OK16(bC, ok);
                    if (ok) { CONS16(bC, 16, accA0, accA1); done |= 4; } else LD16(bC, 16);
                }
                if (!(done & 8)) {
                    int ok; OK16(bD, ok);
                    if (ok) { CONS16(bD, 24, accB0, accB1); done |= 8; } else LD16(bD, 24);
                }
                if (done != 0xF) __builtin_amdgcn_s_sleep(1);
            }
        }

        // ---- tanh, encode epoch bits, two 8B coalesced AGSTs ----
        {
            const floatx4 acc0 = accA0 + accB0;
            const floatx4 acc1 = accA1 + accB1;
            const int cc = 1 + ((t - 1) % 15);     // code(t), never 0 (=poison)
            short* hp = Hg + (size_t)(t & 1) * HS + wroff;
            u64 p0 = 0, p1 = 0;
            #pragma unroll
            for (int r = 0; r < 4; ++r) {
                const unsigned bit = ((unsigned)cc >> r) & 1u;
                p0 |= ((u64)bf15e(fast_tanh(acc0[r] + bias[0][r]), bit)) << (16 * r);
                p1 |= ((u64)bf15e(fast_tanh(acc1[r] + bias[1][r]), bit)) << (16 * r);
            }
            AGST((u64*)(hp), p0);            // ct=0
            AGST((u64*)(hp + 256), p1);      // ct=1 (+2*128 shorts)
            // fire-and-forget: words self-validate at consumers
        }
    }
}

// out[b][o] = sum_k h[b][k]*W2[k][o] + b2. Final h (t=128 -> parity 0) is in
// fragment layout; decode while staging via AGLD into LDS in natural order.
__global__ __launch_bounds__(256) void readout_kernel(
    const short* __restrict__ Hfin, const float* __restrict__ W2,
    const float* __restrict__ b2, float* __restrict__ out)
{
    const int o  = threadIdx.x;
    const int b0 = blockIdx.x * 4;
    __shared__ u64 hs8[4 * DH / 4];            // [row][col/4], 8 KB
    for (int ch = o; ch < 4 * DH / 4; ch += 256) {
        const int row  = ch >> 8;              // 0..3
        const int col0 = (ch & 255) * 4;       // 0,4,..,1020
        const int rr   = b0 + row;
        const int gmr  = rr >> 5, rt = (rr >> 4) & 1, lrr = rr & 15;
        const int ks   = col0 >> 5, qq = (col0 >> 3) & 3, j0 = col0 & 7;
        const u64* src = (const u64*)(Hfin + (size_t)gmr * GSTRIDE + rt * 16384 +
                                      ks * 512 + qq * 128 + lrr * 8 + j0);
        hs8[ch] = AGLD(src);
    }
    __syncthreads();
    const unsigned* h0 = (const unsigned*)&hs8[0 * 256];
    const unsigned* h1 = (const unsigned*)&hs8[1 * 256];
    const unsigned* h2 = (const unsigned*)&hs8[2 * 256];
    const unsigned* h3 = (const unsigned*)&hs8[3 * 256];
    float a0 = 0.f, a1 = 0.f, a2 = 0.f, a3 = 0.f;
    for (int k2 = 0; k2 < DH / 2; ++k2) {
        float w0 = W2[(2 * k2)     * DOUT + o];
        float w1 = W2[(2 * k2 + 1) * DOUT + o];
        unsigned p0 = h0[k2], p1 = h1[k2], p2 = h2[k2], p3 = h3[k2];
        a0 += __builtin_bit_cast(float, p0 << 16) * w0 + __builtin_bit_cast(float, p0 & 0xffff0000u) * w1;
        a1 += __builtin_bit_cast(float, p1 << 16) * w0 + __builtin_bit_cast(float, p1 & 0xffff0000u) * w1;
        a2 += __builtin_bit_cast(float, p2 << 16) * w0 + __builtin_bit_cast(float, p2 & 0xffff0000u) * w1;
        a3 += __builtin_bit_cast(float, p3 << 16) * w0 + __builtin_bit_cast(float, p3 & 0xffff0000u) * w1;
    }
    const float bias = b2[0];
    out[(b0 + 0) * DOUT + o] = a0 + bias;
    out[(b0 + 1) * DOUT + o] = a1 + bias;
    out[(b0 + 2) * DOUT + o] = a2 + bias;
    out[(b0 + 3) * DOUT + o] = a3 + bias;
}

extern "C" void kernel_launch(void* const* d_in, const int* in_sizes, int n_in,
                              void* d_out, int out_size, void* d_ws, size_t ws_size,
                              hipStream_t stream) {
    (void)in_sizes; (void)n_in; (void)out_size; (void)ws_size;
    const float* xs  = (const float*)d_in[0];   // [128,256,256]
    const float* W1x = (const float*)d_in[1];   // [256,1024]
    const float* W1h = (const float*)d_in[2];   // [1024,1024]
    const float* b1  = (const float*)d_in[3];   // [1024]
    const float* W2  = (const float*)d_in[4];   // [1024,256]
    const float* b2  = (const float*)d_in[5];   // scalar
    float* out = (float*)d_out;                 // [256,256]

    // ws: H parity double buffer (1 MB), fragment layout. No flags, no memset:
    // 0xAA poison -> code 0, never matches any expected code (1..15) -> retry.
    short* Hbuf = (short*)d_ws;

    rnn_steps_kernel<<<dim3(NGM, NGN), 128, 0, stream>>>(xs, W1x, W1h, b1, Hbuf);
    // t=128 -> parity 0 holds h_128
    readout_kernel<<<dim3(BB / 4), 256, 0, stream>>>(Hbuf, W2, b2, out);
}

// Round 2
// 674.427 us; speedup vs baseline: 1.5389x; 1.5389x over previous
//
#include <hip/hip_runtime.h>
#include <hip/hip_bf16.h>
#include <math.h>

// Problem constants
#define TT   128
#define BB   256
#define DIN  256
#define DH   1024
#define DOUT 256

// R3-proven shape: 8 row-groups (32 rows) x 32 col-blocks (32 cols), 128 thr,
// 256 blocks, 64KB LDS. R9 flagless sync (epoch bit stolen from each bf16 LSB;
// every 8B word self-validates; AGLD/AGST agent-scope only; no fences, no
// flags, no barriers in the loop). R11: H in MFMA B-fragment order so the
// exchange is fully coalesced.
//
// R12 POST-MORTEM: deep prefetch + round-robin retry was a RETRY STORM (64
// stale loads reissued per poll pass across all waves; FETCH +8MB, dur +35%).
// Polling with 16-load bursts is the real cost: each poll cycle = full
// multi-line RTT, and the polls generate the traffic that slows producers.
//
// R13: ONE-LOAD PROBE. Each 1KB fragment is written by exactly one producer
// wave, so one u64 per fragment proxies its readiness. Lane l probes fragment
// (l&31) -> a SINGLE global_load checks the whole 32-fragment h-tile. Step:
//   issue probe -> x-phase (xs preloaded in regs one step ahead) -> fire xs
//   loads for t+1 -> probe-spin (1 load + s_sleep per cycle) -> chained
//   2-deep LD16/CONS16 (validates first-try; OK16 retry kept as safety net
//   for the rare p0/p1 same-thread store-order race) -> tanh/store.
// Keeps R12's 4 accumulator chains (halved dependent-MFMA depth) and the xs
// register pipeline; kills the retry storm.
#define NGM 8
#define MR  32
#define NGN 32
#define NC  32

typedef float  floatx4 __attribute__((ext_vector_type(4)));
typedef short  shortx8 __attribute__((ext_vector_type(8)));
typedef unsigned long long u64;

#define CMASK 0x0001000100010001ULL
#define GSTRIDE 32768           // shorts per group slab (2*32*4*16*8)

__device__ __forceinline__ short f2bf(float f) {
    union { float f; unsigned u; } v; v.f = f;
    unsigned r = v.u + 0x7fffu + ((v.u >> 16) & 1u);   // RNE, inputs never NaN
    return (short)(r >> 16);
}

// RNE to the bf16 grid restricted to LSB==bit (step 2 ulp): err <= 1 ulp bf16
__device__ __forceinline__ unsigned short bf15e(float v, unsigned bit) {
    union { float f; unsigned u; } x; x.f = v;
    unsigned ua = x.u - (bit << 16);
    unsigned k  = (ua + 0xFFFFu + ((ua >> 17) & 1u)) >> 17;
    return (unsigned short)((k << 1) | bit);
}

__device__ __forceinline__ shortx8 mk8(u64 lo, u64 hi) {
    union { struct { u64 a, b; } s; shortx8 v; } u;
    u.s.a = lo; u.s.b = hi;
    return u.v;
}

__device__ __forceinline__ float fast_tanh(float z) {
    float e = __expf(2.0f * fabsf(z));
    float r = 1.0f - 2.0f / (e + 1.0f);
    return copysignf(r, z);
}

#define AGLD(p)    __hip_atomic_load((p),  __ATOMIC_RELAXED, __HIP_MEMORY_SCOPE_AGENT)
#define AGST(p, v) __hip_atomic_store((p), (v), __ATOMIC_RELAXED, __HIP_MEMORY_SCOPE_AGENT)

// hfr = group slab base + rt*16384 + q*128 + lr*8 ; frag ks at +ks*512.
// One chunk = 8 ks fragments = 16 u64 AGLDs, COALESCED across lanes.
#define LD16(buf, base) do { \
    _Pragma("unroll") \
    for (int _j = 0; _j < 8; ++_j) { \
        const u64* _p = (const u64*)(hfr + ((base) + _j) * 512); \
        buf[2 * _j]     = AGLD(_p); \
        buf[2 * _j + 1] = AGLD(_p + 1); \
    } } while (0)
#define OK16(buf, okvar) do { \
    int _o = 1; \
    _Pragma("unroll") \
    for (int _j = 0; _j < 16; ++_j) _o &= ((buf[_j] & CMASK) == pat); \
    okvar = __all(_o); } while (0)
#define WAITVALID(buf, base) do { \
    int _okk; OK16(buf, _okk); \
    while (!_okk) { __builtin_amdgcn_s_sleep(1); LD16(buf, base); OK16(buf, _okk); } \
    } while (0)
#define CONS16(buf, base, accX, accY) do { \
    _Pragma("unroll") \
    for (int _j = 0; _j < 8; ++_j) { \
        shortx8 bfr = mk8(buf[2 * _j], buf[2 * _j + 1]); \
        shortx8 a0 = *(const shortx8*)&WhL[(base) + _j][0][q][lr][0]; \
        shortx8 a1 = *(const shortx8*)&WhL[(base) + _j][1][q][lr][0]; \
        accX = __builtin_amdgcn_mfma_f32_16x16x32_bf16(a0, bfr, accX, 0, 0, 0); \
        accY = __builtin_amdgcn_mfma_f32_16x16x32_bf16(a1, bfr, accY, 0, 0, 0); \
    } } while (0)

__global__ __launch_bounds__(128, 1) void rnn_steps_kernel(
    const float* __restrict__ xs, const float* __restrict__ W1x,
    const float* __restrict__ W1h, const float* __restrict__ b1,
    short* __restrict__ Hbuf)
{
    const int gm  = blockIdx.x;   // 0..7 row group
    const int gn  = blockIdx.y;   // 0..31 col block
    const int tid = threadIdx.x;
    const int w   = tid >> 6;     // wave -> 16-row tile
    const int l   = tid & 63;
    const int lr  = l & 15;
    const int q   = l >> 4;       // MFMA k-quad

    const int r0 = gm * MR;
    const int c0 = gn * NC;

    // W1h slice as MFMA A-fragments in LDS (R3-proven layout)
    __shared__ short WhL[DH / 32][2][4][16][8];   // 64 KB
    for (int idx = tid; idx < (DH / 32) * 2 * 4 * 16; idx += 128) {
        const int c  = idx & 15;
        const int qq = (idx >> 4) & 3;
        const int ct = (idx >> 6) & 1;
        const int ks = idx >> 7;
        shortx8 f;
        #pragma unroll
        for (int j = 0; j < 8; ++j)
            f[j] = f2bf(W1h[(size_t)(ks * 32 + qq * 8 + j) * DH + c0 + ct * 16 + c]);
        *(shortx8*)&WhL[ks][ct][qq][c][0] = f;
    }
    // W1x A-fragments register-resident (32 VGPRs)
    shortx8 wx[2][8];
    #pragma unroll
    for (int ct = 0; ct < 2; ++ct)
        #pragma unroll
        for (int ks = 0; ks < 8; ++ks) {
            shortx8 f;
            #pragma unroll
            for (int j = 0; j < 8; ++j)
                f[j] = f2bf(W1x[(size_t)(ks * 32 + q * 8 + j) * DH + c0 + ct * 16 + lr]);
            wx[ct][ks] = f;
        }
    __syncthreads();   // WhL ready; no barriers after this point

    floatx4 bias[2];
    #pragma unroll
    for (int ct = 0; ct < 2; ++ct)
        #pragma unroll
        for (int r = 0; r < 4; ++r) bias[ct][r] = b1[c0 + ct * 16 + q * 4 + r];

    const int myrow = r0 + w * 16 + lr;        // xs rows (unchanged)
    const size_t HS = (size_t)BB * DH;         // shorts per version

    // fragment-layout bases (consumer reads its own row-tile w)
    short* const Hg   = Hbuf + gm * GSTRIDE;
    const int rdoff   = w * 16384 + q * 128 + lr * 8;
    // producer store offsets (ks=gn): [w][gn][ct*2+(q>>1)][lr][(q&1)*4]
    const int wroff   = w * 16384 + gn * 512 + (q >> 1) * 128 + lr * 8 + (q & 1) * 4;
    // probe offset: lane l watches fragment (l&31) of its wave's row tile
    const int proff   = w * 16384 + (l & 31) * 512;

    // ---- xs register pipeline: xf holds x_t, loaded during step t-1 ----
    floatx4 xf[16];
    {
        const float* xrow = xs + (size_t)myrow * DIN + q * 8;   // t = 1
        #pragma unroll
        for (int ks = 0; ks < 8; ++ks) {
            xf[2 * ks]     = *(const floatx4*)(xrow + ks * 32);
            xf[2 * ks + 1] = *(const floatx4*)(xrow + ks * 32 + 4);
        }
    }

    for (int t = 1; t <= TT; ++t) {
        const short* const hfr = Hg + (size_t)((t - 1) & 1) * HS + rdoff;
        // expected epoch code for h_{t-1}: 1+((t-2)%15) in [1,15]; t=1 unused.
        const int pc = (t >= 2) ? (1 + ((t - 2) % 15)) : 0;
        const u64 pat = ((u64)(pc & 1)) | ((u64)((pc >> 1) & 1) << 16) |
                        ((u64)((pc >> 2) & 1) << 32) | ((u64)((pc >> 3) & 1) << 48);

        // ---- issue the one-load readiness probe; result checked after x ----
        const u64* const pp = (const u64*)(Hg + (size_t)((t - 1) & 1) * HS + proff);
        u64 pv = 0;
        if (t > 1) pv = AGLD(pp);

        floatx4 accA0 = {0.f, 0.f, 0.f, 0.f}, accA1 = {0.f, 0.f, 0.f, 0.f};
        floatx4 accB0 = {0.f, 0.f, 0.f, 0.f}, accB1 = {0.f, 0.f, 0.f, 0.f};

        // ---- x_t @ W1x from the register pipeline (no memory on this path) ----
        #pragma unroll
        for (int ks = 0; ks < 8; ++ks) {
            floatx4 x0 = xf[2 * ks], x1 = xf[2 * ks + 1];
            shortx8 b;
            b[0] = f2bf(x0[0]); b[1] = f2bf(x0[1]); b[2] = f2bf(x0[2]); b[3] = f2bf(x0[3]);
            b[4] = f2bf(x1[0]); b[5] = f2bf(x1[1]); b[6] = f2bf(x1[2]); b[7] = f2bf(x1[3]);
            accA0 = __builtin_amdgcn_mfma_f32_16x16x32_bf16(wx[0][ks], b, accA0, 0, 0, 0);
            accA1 = __builtin_amdgcn_mfma_f32_16x16x32_bf16(wx[1][ks], b, accA1, 0, 0, 0);
        }

        // ---- fire xs loads for step t+1 (consumed next iteration) ----
        if (t < TT) {
            const float* xrow = xs + ((size_t)t * BB + myrow) * DIN + q * 8;
            #pragma unroll
            for (int ks = 0; ks < 8; ++ks) {
                xf[2 * ks]     = *(const floatx4*)(xrow + ks * 32);
                xf[2 * ks + 1] = *(const floatx4*)(xrow + ks * 32 + 4);
            }
        }

        // ---- h_{t-1} @ W1h ----
        if (t > 1) {
            // probe-spin: one 8B load per cycle watches all 32 fragments
            while (!__all((pv & CMASK) == pat)) {
                __builtin_amdgcn_s_sleep(2);
                pv = AGLD(pp);
            }
            // tile is ready: chained 2-deep burst load / validate / consume.
            // OK16 retry survives the rare p0/p1 same-thread store-order race.
            u64 A[16], B[16];
            LD16(A, 0);  LD16(B, 8);
            WAITVALID(A, 0);  CONS16(A, 0,  accA0, accA1);
            LD16(A, 16);
            WAITVALID(B, 8);  CONS16(B, 8,  accB0, accB1);
            LD16(B, 24);
            WAITVALID(A, 16); CONS16(A, 16, accA0, accA1);
            WAITVALID(B, 24); CONS16(B, 24, accB0, accB1);
        }

        // ---- tanh, encode epoch bits, two 8B coalesced AGSTs ----
        {
            const floatx4 acc0 = accA0 + accB0;
            const floatx4 acc1 = accA1 + accB1;
            const int cc = 1 + ((t - 1) % 15);     // code(t), never 0 (=poison)
            short* hp = Hg + (size_t)(t & 1) * HS + wroff;
            u64 p0 = 0, p1 = 0;
            #pragma unroll
            for (int r = 0; r < 4; ++r) {
                const unsigned bit = ((unsigned)cc >> r) & 1u;
                p0 |= ((u64)bf15e(fast_tanh(acc0[r] + bias[0][r]), bit)) << (16 * r);
                p1 |= ((u64)bf15e(fast_tanh(acc1[r] + bias[1][r]), bit)) << (16 * r);
            }
            AGST((u64*)(hp), p0);            // ct=0
            AGST((u64*)(hp + 256), p1);      // ct=1 (+2*128 shorts)
            // fire-and-forget: words self-validate at consumers
        }
    }
}

// out[b][o] = sum_k h[b][k]*W2[k][o] + b2. Final h (t=128 -> parity 0) is in
// fragment layout; decode while staging via AGLD into LDS in natural order.
__global__ __launch_bounds__(256) void readout_kernel(
    const short* __restrict__ Hfin, const float* __restrict__ W2,
    const float* __restrict__ b2, float* __restrict__ out)
{
    const int o  = threadIdx.x;
    const int b0 = blockIdx.x * 4;
    __shared__ u64 hs8[4 * DH / 4];            // [row][col/4], 8 KB
    for (int ch = o; ch < 4 * DH / 4; ch += 256) {
        const int row  = ch >> 8;              // 0..3
        const int col0 = (ch & 255) * 4;       // 0,4,..,1020
        const int rr   = b0 + row;
        const int gmr  = rr >> 5, rt = (rr >> 4) & 1, lrr = rr & 15;
        const int ks   = col0 >> 5, qq = (col0 >> 3) & 3, j0 = col0 & 7;
        const u64* src = (const u64*)(Hfin + (size_t)gmr * GSTRIDE + rt * 16384 +
                                      ks * 512 + qq * 128 + lrr * 8 + j0);
        hs8[ch] = AGLD(src);
    }
    __syncthreads();
    const unsigned* h0 = (const unsigned*)&hs8[0 * 256];
    const unsigned* h1 = (const unsigned*)&hs8[1 * 256];
    const unsigned* h2 = (const unsigned*)&hs8[2 * 256];
    const unsigned* h3 = (const unsigned*)&hs8[3 * 256];
    float a0 = 0.f, a1 = 0.f, a2 = 0.f, a3 = 0.f;
    for (int k2 = 0; k2 < DH / 2; ++k2) {
        float w0 = W2[(2 * k2)     * DOUT + o];
        float w1 = W2[(2 * k2 + 1) * DOUT + o];
        unsigned p0 = h0[k2], p1 = h1[k2], p2 = h2[k2], p3 = h3[k2];
        a0 += __builtin_bit_cast(float, p0 << 16) * w0 + __builtin_bit_cast(float, p0 & 0xffff0000u) * w1;
        a1 += __builtin_bit_cast(float, p1 << 16) * w0 + __builtin_bit_cast(float, p1 & 0xffff0000u) * w1;
        a2 += __builtin_bit_cast(float, p2 << 16) * w0 + __builtin_bit_cast(float, p2 & 0xffff0000u) * w1;
        a3 += __builtin_bit_cast(float, p3 << 16) * w0 + __builtin_bit_cast(float, p3 & 0xffff0000u) * w1;
    }
    const float bias = b2[0];
    out[(b0 + 0) * DOUT + o] = a0 + bias;
    out[(b0 + 1) * DOUT + o] = a1 + bias;
    out[(b0 + 2) * DOUT + o] = a2 + bias;
    out[(b0 + 3) * DOUT + o] = a3 + bias;
}

extern "C" void kernel_launch(void* const* d_in, const int* in_sizes, int n_in,
                              void* d_out, int out_size, void* d_ws, size_t ws_size,
                              hipStream_t stream) {
    (void)in_sizes; (void)n_in; (void)out_size; (void)ws_size;
    const float* xs  = (const float*)d_in[0];   // [128,256,256]
    const float* W1x = (const float*)d_in[1];   // [256,1024]
    const float* W1h = (const float*)d_in[2];   // [1024,1024]
    const float* b1  = (const float*)d_in[3];   // [1024]
    const float* W2  = (const float*)d_in[4];   // [1024,256]
    const float* b2  = (const float*)d_in[5];   // scalar
    float* out = (float*)d_out;                 // [256,256]

    // ws: H parity double buffer (1 MB), fragment layout. No flags, no memset:
    // 0xAA poison -> code 0, never matches any expected code (1..15) -> retry.
    short* Hbuf = (short*)d_ws;

    rnn_steps_kernel<<<dim3(NGM, NGN), 128, 0, stream>>>(xs, W1x, W1h, b1, Hbuf);
    // t=128 -> parity 0 holds h_128
    readout_kernel<<<dim3(BB / 4), 256, 0, stream>>>(Hbuf, W2, b2, out);
}